// Round 2
// baseline (1636.982 us; speedup 1.0000x reference)
//
#include <hip/hip_runtime.h>
#include <hip/hip_bf16.h>
#include <cstdint>
#include <cstddef>

// Problem constants
#define BATCH   8192
#define DIM     768
#define NTOT    6291456      // BATCH*DIM
#define NLAYERS 4

// ---------------------------------------------------------------------------
// Threefry-2x32 (matches jax/_src/prng.py exactly; 20 rounds, 5 key injections)
// ---------------------------------------------------------------------------
__host__ __device__ __forceinline__ uint32_t rotl32(uint32_t v, int d) {
  return (v << d) | (v >> (32 - d));
}

__host__ __device__ __forceinline__ void threefry2x32(
    uint32_t k0, uint32_t k1, uint32_t x0, uint32_t x1,
    uint32_t& o0, uint32_t& o1) {
  uint32_t ks2 = k0 ^ k1 ^ 0x1BD11BDAu;
  x0 += k0; x1 += k1;
#define TF_R(r) { x0 += x1; x1 = rotl32(x1, (r)) ^ x0; }
  TF_R(13) TF_R(15) TF_R(26) TF_R(6)
  x0 += k1; x1 += ks2 + 1u;
  TF_R(17) TF_R(29) TF_R(16) TF_R(24)
  x0 += ks2; x1 += k0 + 2u;
  TF_R(13) TF_R(15) TF_R(26) TF_R(6)
  x0 += k0; x1 += k1 + 3u;
  TF_R(17) TF_R(29) TF_R(16) TF_R(24)
  x0 += k1; x1 += ks2 + 4u;
  TF_R(13) TF_R(15) TF_R(26) TF_R(6)
  x0 += ks2; x1 += k0 + 5u;
#undef TF_R
  o0 = x0; o1 = x1;
}

__device__ __forceinline__ double sigmoid_d(double x) {
  return 1.0 / (1.0 + exp(-x));
}

// ---------------------------------------------------------------------------
// Kernel 1: embedding gather -> x_d and x_s (identical initial x)
// ---------------------------------------------------------------------------
__global__ __launch_bounds__(256) void gather_kernel(
    const int* __restrict__ x_p, const int* __restrict__ x_a,
    const int* __restrict__ x_c,
    const float* __restrict__ E0, const float* __restrict__ E1,
    const float* __restrict__ E2,
    float* __restrict__ xd, float* __restrict__ xs) {
  int j = blockIdx.x * 256 + threadIdx.x;      // 0 .. NTOT-1
  int b = j / DIM;
  int f = j - b * DIM;
  int half = f / 384;          // 0 or 1
  int w = f - half * 384;      // 0..383
  int t = w >> 7;              // table 0..2
  int c = (w & 127) + (half << 7);
  int idx;
  const float* E;
  if (t == 0)      { E = E0; idx = x_p[b]; }
  else if (t == 1) { E = E1; idx = x_a[b]; }
  else             { E = E2; idx = x_c[b]; }
  float v = E[(size_t)idx * 256 + c];
  xd[j] = v;
  xs[j] = v;
}

// ---------------------------------------------------------------------------
// Kernel 1b: transpose W[layer] for both nets: Wt[net][k][o] = W[net][layer][o][k]
// ---------------------------------------------------------------------------
__global__ __launch_bounds__(256) void transpose_w_kernel(
    const float* __restrict__ Wd, const float* __restrict__ Ws,
    float* __restrict__ Wt, int layer) {
  __shared__ float tile[32][33];
  const int net = blockIdx.z;
  const float* W = (net ? Ws : Wd) + (size_t)layer * DIM * DIM;
  float* out = Wt + (size_t)net * DIM * DIM;
  const int o0 = blockIdx.y * 32, k0 = blockIdx.x * 32;
  const int lx = threadIdx.x & 31, ly = threadIdx.x >> 5;   // 32 x 8
#pragma unroll
  for (int r = 0; r < 32; r += 8)
    tile[ly + r][lx] = W[(size_t)(o0 + ly + r) * DIM + k0 + lx];
  __syncthreads();
#pragma unroll
  for (int r = 0; r < 32; r += 8)
    out[(size_t)(k0 + ly + r) * DIM + o0 + lx] = tile[lx][ly + r];
}

// ---------------------------------------------------------------------------
// Kernel 2: register GEMM, B from SGPRs.
//   cross[row][n0+j] = sum_k A[row][k] * Wt[k][n0+j] + bias[n0+j]
// lane = row (M), acc index = column (N-tile 32). B loads are wave-uniform
// -> compiler scalarizes to s_load; FMA reads B as the SGPR operand.
// No LDS, no __syncthreads. A row-chunk double-buffered in VGPRs.
// Epilogue: bias, store cross, fp64 per-block (sum,sumsq) partials.
// ---------------------------------------------------------------------------
__global__ __launch_bounds__(256) void gemm_sgpr_kernel(
    const float* __restrict__ xd, const float* __restrict__ xs,
    const float* __restrict__ Wt,
    const float* __restrict__ bd, const float* __restrict__ bs,
    float* __restrict__ crd, float* __restrict__ crs,
    double* __restrict__ partials, int layer) {
  const int net = blockIdx.z;
  const float* A    = net ? xs : xd;
  const float* Wk   = Wt + (size_t)net * DIM * DIM;
  const float* bias = (net ? bs : bd) + layer * DIM;
  float* C          = net ? crs : crd;

  const int n0  = blockIdx.x * 32;
  const int row = blockIdx.y * 256 + threadIdx.x;
  const float* Arow = A + (size_t)row * DIM;

  float acc[32];
#pragma unroll
  for (int j = 0; j < 32; ++j) acc[j] = 0.0f;

  float4 cur[8], nxt[8];
#pragma unroll
  for (int i = 0; i < 8; ++i) cur[i] = *(const float4*)(Arow + i * 4);

  for (int k0 = 0; k0 < DIM; k0 += 32) {
    if (k0 + 32 < DIM) {
#pragma unroll
      for (int i = 0; i < 8; ++i)
        nxt[i] = *(const float4*)(Arow + k0 + 32 + i * 4);
    }
#pragma unroll
    for (int kk = 0; kk < 8; ++kk) {
      float a4[4] = {cur[kk].x, cur[kk].y, cur[kk].z, cur[kk].w};
#pragma unroll
      for (int t = 0; t < 4; ++t) {
        const float4* bp =
            (const float4*)(Wk + (size_t)(k0 + kk * 4 + t) * DIM + n0);
        float a = a4[t];
#pragma unroll
        for (int j = 0; j < 8; ++j) {
          float4 bv = bp[j];   // wave-uniform -> s_load, SGPR operand in FMA
          acc[4 * j + 0] = fmaf(a, bv.x, acc[4 * j + 0]);
          acc[4 * j + 1] = fmaf(a, bv.y, acc[4 * j + 1]);
          acc[4 * j + 2] = fmaf(a, bv.z, acc[4 * j + 2]);
          acc[4 * j + 3] = fmaf(a, bv.w, acc[4 * j + 3]);
        }
      }
    }
    if (k0 + 32 < DIM) {
#pragma unroll
      for (int i = 0; i < 8; ++i) cur[i] = nxt[i];
    }
  }

  // epilogue: bias, store, fp64 sum/sumsq partials
  double s = 0.0, q = 0.0;
#pragma unroll
  for (int j = 0; j < 8; ++j) {
    float4 bv = *(const float4*)(bias + n0 + 4 * j);
    float4 o;
    o.x = acc[4 * j + 0] + bv.x;
    o.y = acc[4 * j + 1] + bv.y;
    o.z = acc[4 * j + 2] + bv.z;
    o.w = acc[4 * j + 3] + bv.w;
    s += (double)o.x + (double)o.y + (double)o.z + (double)o.w;
    q += (double)o.x * o.x + (double)o.y * o.y +
         (double)o.z * o.z + (double)o.w * o.w;
    *(float4*)(C + (size_t)row * DIM + n0 + 4 * j) = o;
  }
#pragma unroll
  for (int off = 32; off > 0; off >>= 1) {
    s += __shfl_down(s, off);
    q += __shfl_down(q, off);
  }
  __shared__ double red[4][2];
  const int wave = threadIdx.x >> 6, lane = threadIdx.x & 63;
  if (lane == 0) { red[wave][0] = s; red[wave][1] = q; }
  __syncthreads();
  if (threadIdx.x == 0) {
    double S = red[0][0] + red[1][0] + red[2][0] + red[3][0];
    double Q = red[0][1] + red[1][1] + red[2][1] + red[3][1];
    int bid = blockIdx.y * gridDim.x + blockIdx.x;   // 0..767
    partials[((size_t)net * 768 + bid) * 2 + 0] = S;
    partials[((size_t)net * 768 + bid) * 2 + 1] = Q;
  }
}

// ---------------------------------------------------------------------------
// Kernel 3: reduce 768 per-block partials -> stats[net] = {sum, sumsq}
// ---------------------------------------------------------------------------
__global__ __launch_bounds__(256) void finalize_stats_kernel(
    const double* __restrict__ partials, double* __restrict__ stats) {
  int net = blockIdx.x;
  const double* P = partials + (size_t)net * 768 * 2;
  int tid = threadIdx.x;
  double s = 0.0, q = 0.0;
  for (int i = tid; i < 768; i += 256) {
    s += P[i * 2 + 0];
    q += P[i * 2 + 1];
  }
#pragma unroll
  for (int off = 32; off > 0; off >>= 1) {
    s += __shfl_down(s, off);
    q += __shfl_down(q, off);
  }
  __shared__ double red[4][2];
  int wave = tid >> 6, lane = tid & 63;
  if (lane == 0) { red[wave][0] = s; red[wave][1] = q; }
  __syncthreads();
  if (tid == 0) {
    stats[net * 2 + 0] = red[0][0] + red[1][0] + red[2][0] + red[3][0];
    stats[net * 2 + 1] = red[0][1] + red[1][1] + red[2][1] + red[3][1];
  }
}

// ---------------------------------------------------------------------------
// Kernel 4: full-tensor layernorm -> sigmoid -> threefry bernoulli mask ->
//           x += cross*mask. (partitionable mapping: bits[j] = o0^o1 of
//           threefry(key, hi=0, lo=j))
// ---------------------------------------------------------------------------
__global__ __launch_bounds__(256) void mask_update_kernel(
    float* __restrict__ xd, float* __restrict__ xs,
    const float* __restrict__ crd, const float* __restrict__ crs,
    const double* __restrict__ stats,
    uint32_t kd0, uint32_t kd1, uint32_t ks0, uint32_t ks1) {
  const int net = blockIdx.y;
  float* x = net ? xs : xd;
  const float* cr = net ? crs : crd;
  const uint32_t k0 = net ? ks0 : kd0;
  const uint32_t k1 = net ? ks1 : kd1;

  const double invN = 1.0 / (double)NTOT;
  double meand = stats[net * 2 + 0] * invN;
  double vard  = stats[net * 2 + 1] * invN - meand * meand;
  float m  = (float)meand;
  float v  = (float)vard;
  float sv = v + 1e-5f;
  float rs = (float)(1.0 / sqrt((double)sv));

  uint32_t j = blockIdx.x * 256u + threadIdx.x;  // 0..NTOT-1
  float c = cr[j];
  float ln = (c - m) * rs;
  float p = (float)sigmoid_d((double)ln);
  uint32_t o0, o1;
  threefry2x32(k0, k1, 0u, j, o0, o1);
  uint32_t bits = o0 ^ o1;
  float u = __uint_as_float(0x3F800000u | (bits >> 9)) - 1.0f;
  if (u < p) x[j] = x[j] + c;
}

// ---------------------------------------------------------------------------
// Kernel 5: heads. One wave per row: 4 dot products, sigmoids, y_pred_d,
// per-block fp64 BCE partials.
// ---------------------------------------------------------------------------
__global__ __launch_bounds__(256) void head_kernel(
    const float* __restrict__ xd, const float* __restrict__ xs,
    const float* __restrict__ wfd, const float* __restrict__ wfs,
    const float* __restrict__ bfd_p, const float* __restrict__ bfs_p,
    const float* __restrict__ y_true,
    float* __restrict__ out, double* __restrict__ bce_part) {
  const int wave = threadIdx.x >> 6;
  const int lane = threadIdx.x & 63;
  const int row = blockIdx.x * 4 + wave;
  const float* xdr = xd + (size_t)row * DIM;
  const float* xsr = xs + (size_t)row * DIM;

  float dd = 0.f, dsw = 0.f, sd = 0.f, ssw = 0.f;
  for (int t = lane; t < DIM; t += 64) {
    float vd = xdr[t], vs = xsr[t];
    float wd = wfd[t], ws = wfs[t];
    dd  = fmaf(vd, wd, dd);
    dsw = fmaf(vd, ws, dsw);
    sd  = fmaf(vs, wd, sd);
    ssw = fmaf(vs, ws, ssw);
  }
#pragma unroll
  for (int off = 32; off > 0; off >>= 1) {
    dd  += __shfl_down(dd, off);
    dsw += __shfl_down(dsw, off);
    sd  += __shfl_down(sd, off);
    ssw += __shfl_down(ssw, off);
  }
  __shared__ double redd[4], reds[4];
  if (lane == 0) {
    float bfd = *bfd_p, bfs = *bfs_p;
    double sdd = sigmoid_d((double)(dd + bfd));    // fc_d(x_d)
    double ssd = sigmoid_d((double)(dsw + bfs));   // fc_s(x_d)
    double sds = sigmoid_d((double)(sd + bfd));    // fc_d(x_s)
    double sss = sigmoid_d((double)(ssw + bfs));   // fc_s(x_s)
    double ypd = 0.5 * (sdd + sss);
    double yps = 0.5 * (sds + ssd);
    out[row] = (float)ypd;
    double y = (double)y_true[row];
    redd[wave] = -(y * log(ypd) + (1.0 - y) * log(1.0 - ypd));
    reds[wave] = -(y * log(yps) + (1.0 - y) * log(1.0 - yps));
  }
  __syncthreads();
  if (threadIdx.x == 0) {
    bce_part[(size_t)blockIdx.x * 2 + 0] = redd[0] + redd[1] + redd[2] + redd[3];
    bce_part[(size_t)blockIdx.x * 2 + 1] = reds[0] + reds[1] + reds[2] + reds[3];
  }
}

// ---------------------------------------------------------------------------
// Kernel 6: reduce BCE partials -> tri_loss
// ---------------------------------------------------------------------------
__global__ __launch_bounds__(256) void loss_kernel(
    const double* __restrict__ bce_part, float* __restrict__ out_tri) {
  int tid = threadIdx.x;
  double sdl = 0.0, ssl = 0.0;
  for (int i = tid; i < 2048; i += 256) {
    sdl += bce_part[i * 2 + 0];
    ssl += bce_part[i * 2 + 1];
  }
#pragma unroll
  for (int off = 32; off > 0; off >>= 1) {
    sdl += __shfl_down(sdl, off);
    ssl += __shfl_down(ssl, off);
  }
  __shared__ double red[4][2];
  int wave = tid >> 6, lane = tid & 63;
  if (lane == 0) { red[wave][0] = sdl; red[wave][1] = ssl; }
  __syncthreads();
  if (tid == 0) {
    double loss_d = (red[0][0] + red[1][0] + red[2][0] + red[3][0]) / (double)BATCH;
    double loss_s = (red[0][1] + red[1][1] + red[2][1] + red[3][1]) / (double)BATCH;
    double bce = loss_d + loss_s;
    double wd = fmax(0.0, loss_d - bce);
    double ws = fmax(0.0, loss_s - bce);
    out_tri[0] = (float)(bce + wd * loss_d + ws * loss_s);
  }
}

// ---------------------------------------------------------------------------
// Launch
// ---------------------------------------------------------------------------
extern "C" void kernel_launch(void* const* d_in, const int* in_sizes, int n_in,
                              void* d_out, int out_size, void* d_ws, size_t ws_size,
                              hipStream_t stream) {
  const int* x_p = (const int*)d_in[0];
  const int* x_a = (const int*)d_in[1];
  const int* x_c = (const int*)d_in[2];
  const float* y_true = (const float*)d_in[3];
  const float* E0 = (const float*)d_in[4];
  const float* E1 = (const float*)d_in[5];
  const float* E2 = (const float*)d_in[6];
  const float* Wd = (const float*)d_in[7];
  const float* bd = (const float*)d_in[8];
  const float* Ws = (const float*)d_in[9];
  const float* bs = (const float*)d_in[10];
  const float* wfd = (const float*)d_in[11];
  const float* bfd = (const float*)d_in[12];
  const float* wfs = (const float*)d_in[13];
  const float* bfs = (const float*)d_in[14];
  float* out = (float*)d_out;

  // workspace layout
  float* xd  = (float*)d_ws;
  float* xs  = xd + NTOT;
  float* crd = xs + NTOT;
  float* crs = crd + NTOT;
  float* wt  = crs + NTOT;                     // 2 * 768*768 floats
  double* partials = (double*)(wt + 2 * DIM * DIM);  // 2*768*2 doubles
  double* stats    = partials + 2 * 768 * 2;   // 4 doubles
  double* bce_part = stats + 4;                // 2048*2 doubles

  gather_kernel<<<NTOT / 256, 256, 0, stream>>>(x_p, x_a, x_c, E0, E1, E2, xd, xs);

  for (int l = 0; l < NLAYERS; ++l) {
    transpose_w_kernel<<<dim3(24, 24, 2), 256, 0, stream>>>(Wd, Ws, wt, l);
    gemm_sgpr_kernel<<<dim3(24, 32, 2), 256, 0, stream>>>(
        xd, xs, wt, bd, bs, crd, crs, partials, l);
    finalize_stats_kernel<<<2, 256, 0, stream>>>(partials, stats);
    uint32_t kd0, kd1, ks0, ks1;
    threefry2x32(0u, 42u, 0u, (uint32_t)l, kd0, kd1);
    threefry2x32(0u, 42u, 0u, (uint32_t)(4 + l), ks0, ks1);
    mask_update_kernel<<<dim3(NTOT / 256, 2), 256, 0, stream>>>(
        xd, xs, crd, crs, stats, kd0, kd1, ks0, ks1);
  }

  head_kernel<<<BATCH / 4, 256, 0, stream>>>(
      xd, xs, wfd, wfs, bfd, bfs, y_true, out, bce_part);
  loss_kernel<<<1, 256, 0, stream>>>(bce_part, out + BATCH);
}

// Round 3
// 1180.714 us; speedup vs baseline: 1.3864x; 1.3864x over previous
//
#include <hip/hip_runtime.h>
#include <hip/hip_bf16.h>
#include <cstdint>
#include <cstddef>

// Problem constants
#define BATCH   8192
#define DIM     768
#define NTOT    6291456      // BATCH*DIM
#define NLAYERS 4

typedef _Float16 half8 __attribute__((ext_vector_type(8)));
typedef float    f32x4 __attribute__((ext_vector_type(4)));

// ---------------------------------------------------------------------------
// Threefry-2x32 (matches jax/_src/prng.py exactly; 20 rounds, 5 key injections)
// ---------------------------------------------------------------------------
__host__ __device__ __forceinline__ uint32_t rotl32(uint32_t v, int d) {
  return (v << d) | (v >> (32 - d));
}

__host__ __device__ __forceinline__ void threefry2x32(
    uint32_t k0, uint32_t k1, uint32_t x0, uint32_t x1,
    uint32_t& o0, uint32_t& o1) {
  uint32_t ks2 = k0 ^ k1 ^ 0x1BD11BDAu;
  x0 += k0; x1 += k1;
#define TF_R(r) { x0 += x1; x1 = rotl32(x1, (r)) ^ x0; }
  TF_R(13) TF_R(15) TF_R(26) TF_R(6)
  x0 += k1; x1 += ks2 + 1u;
  TF_R(17) TF_R(29) TF_R(16) TF_R(24)
  x0 += ks2; x1 += k0 + 2u;
  TF_R(13) TF_R(15) TF_R(26) TF_R(6)
  x0 += k0; x1 += k1 + 3u;
  TF_R(17) TF_R(29) TF_R(16) TF_R(24)
  x0 += k1; x1 += ks2 + 4u;
  TF_R(13) TF_R(15) TF_R(26) TF_R(6)
  x0 += ks2; x1 += k0 + 5u;
#undef TF_R
  o0 = x0; o1 = x1;
}

__device__ __forceinline__ double sigmoid_d(double x) {
  return 1.0 / (1.0 + exp(-x));
}

// ---------------------------------------------------------------------------
// Kernel 1: embedding gather -> x as f16 hi/lo pairs for both nets
// ---------------------------------------------------------------------------
__global__ __launch_bounds__(256) void gather_kernel(
    const int* __restrict__ x_p, const int* __restrict__ x_a,
    const int* __restrict__ x_c,
    const float* __restrict__ E0, const float* __restrict__ E1,
    const float* __restrict__ E2,
    _Float16* __restrict__ xdh, _Float16* __restrict__ xdl,
    _Float16* __restrict__ xsh, _Float16* __restrict__ xsl) {
  int j = blockIdx.x * 256 + threadIdx.x;      // 0 .. NTOT-1
  int b = j / DIM;
  int f = j - b * DIM;
  int half_ = f / 384;         // 0 or 1
  int w = f - half_ * 384;     // 0..383
  int t = w >> 7;              // table 0..2
  int c = (w & 127) + (half_ << 7);
  int idx;
  const float* E;
  if (t == 0)      { E = E0; idx = x_p[b]; }
  else if (t == 1) { E = E1; idx = x_a[b]; }
  else             { E = E2; idx = x_c[b]; }
  float v = E[(size_t)idx * 256 + c];
  _Float16 h = (_Float16)v;
  _Float16 l = (_Float16)(v - (float)h);
  xdh[j] = h; xdl[j] = l;
  xsh[j] = h; xsl[j] = l;
}

// ---------------------------------------------------------------------------
// Kernel 1b: split all W (both nets, all layers) into f16 hi/lo
// layout: [net][layer][o][k], net-major = concat(Wd, Ws)
// ---------------------------------------------------------------------------
__global__ __launch_bounds__(256) void split_w_kernel(
    const float* __restrict__ Wd, const float* __restrict__ Ws,
    _Float16* __restrict__ Wh, _Float16* __restrict__ Wl) {
  int idx = blockIdx.x * 256 + threadIdx.x;    // 0 .. 2*4*768*768-1
  const int perNet = NLAYERS * DIM * DIM;
  float v = (idx < perNet) ? Wd[idx] : Ws[idx - perNet];
  _Float16 h = (_Float16)v;
  Wh[idx] = h;
  Wl[idx] = (_Float16)(v - (float)h);
}

// ---------------------------------------------------------------------------
// Kernel 2: MFMA GEMM via f16 hi/lo 3-term split.
//   cross[m][n] = sum_k X[m][k] * W[n][k] + bias[n]
// 128x128 block tile, 4 waves in 2x2, each wave 64x64 = 4x4 MFMA 16x16 tiles.
// No LDS staging: A/B fragments load global->VGPR (dwordx4, 64B/row segments);
// W is L2-resident, A re-read 6x via L2/L1.
// acc += Ah*Bh + Al*Bh + Ah*Bl   (lo*lo dropped, ~2^-22 relative)
// Epilogue: bias, store cross fp32, fp64 per-block (sum,sumsq) partials.
// ---------------------------------------------------------------------------
__global__ __launch_bounds__(256, 3) void gemm_mfma_kernel(
    const _Float16* __restrict__ xdh, const _Float16* __restrict__ xdl,
    const _Float16* __restrict__ xsh, const _Float16* __restrict__ xsl,
    const _Float16* __restrict__ Wh, const _Float16* __restrict__ Wl,
    const float* __restrict__ bd, const float* __restrict__ bs,
    float* __restrict__ crd, float* __restrict__ crs,
    double* __restrict__ partials, int layer) {
  const int net = blockIdx.z;
  const _Float16* Ah = net ? xsh : xdh;
  const _Float16* Al = net ? xsl : xdl;
  const _Float16* Bh = Wh + ((size_t)net * NLAYERS + layer) * DIM * DIM;
  const _Float16* Bl = Wl + ((size_t)net * NLAYERS + layer) * DIM * DIM;
  const float* bias = (net ? bs : bd) + layer * DIM;
  float* C = net ? crs : crd;

  const int wave = threadIdx.x >> 6, lane = threadIdx.x & 63;
  const int quad = lane >> 4, l16 = lane & 15;
  const int m0 = blockIdx.y * 128 + (wave >> 1) * 64;   // wave's M base
  const int n0 = blockIdx.x * 128 + (wave & 1) * 64;    // wave's N base

  f32x4 acc[4][4];
#pragma unroll
  for (int i = 0; i < 4; ++i)
#pragma unroll
    for (int j = 0; j < 4; ++j) acc[i][j] = (f32x4){0.f, 0.f, 0.f, 0.f};

  // per-lane fragment base offsets (elements)
  int aoff[4], boff[4];
#pragma unroll
  for (int t = 0; t < 4; ++t) {
    aoff[t] = (m0 + t * 16 + l16) * DIM + quad * 8;
    boff[t] = (n0 + t * 16 + l16) * DIM + quad * 8;
  }

  for (int k0 = 0; k0 < DIM; k0 += 32) {
    half8 ah[4], al[4], bh[4], bl[4];
#pragma unroll
    for (int t = 0; t < 4; ++t) {
      ah[t] = *(const half8*)(Ah + aoff[t] + k0);
      al[t] = *(const half8*)(Al + aoff[t] + k0);
      bh[t] = *(const half8*)(Bh + boff[t] + k0);
      bl[t] = *(const half8*)(Bl + boff[t] + k0);
    }
#pragma unroll
    for (int mt = 0; mt < 4; ++mt)
#pragma unroll
      for (int nt = 0; nt < 4; ++nt) {
        f32x4 a = acc[mt][nt];
        a = __builtin_amdgcn_mfma_f32_16x16x32_f16(ah[mt], bh[nt], a, 0, 0, 0);
        a = __builtin_amdgcn_mfma_f32_16x16x32_f16(al[mt], bh[nt], a, 0, 0, 0);
        a = __builtin_amdgcn_mfma_f32_16x16x32_f16(ah[mt], bl[nt], a, 0, 0, 0);
        acc[mt][nt] = a;
      }
  }

  // epilogue: bias add, store, fp64 sum/sumsq partials
  float biasv[4];
#pragma unroll
  for (int nt = 0; nt < 4; ++nt) biasv[nt] = bias[n0 + nt * 16 + l16];

  double s = 0.0, q = 0.0;
#pragma unroll
  for (int mt = 0; mt < 4; ++mt) {
#pragma unroll
    for (int nt = 0; nt < 4; ++nt) {
      int n = n0 + nt * 16 + l16;
#pragma unroll
      for (int r = 0; r < 4; ++r) {
        int m = m0 + mt * 16 + quad * 4 + r;
        float v = acc[mt][nt][r] + biasv[nt];
        C[(size_t)m * DIM + n] = v;
        s += (double)v;
        q += (double)v * (double)v;
      }
    }
  }
#pragma unroll
  for (int off = 32; off > 0; off >>= 1) {
    s += __shfl_down(s, off);
    q += __shfl_down(q, off);
  }
  __shared__ double red[4][2];
  if (lane == 0) { red[wave][0] = s; red[wave][1] = q; }
  __syncthreads();
  if (threadIdx.x == 0) {
    double S = red[0][0] + red[1][0] + red[2][0] + red[3][0];
    double Q = red[0][1] + red[1][1] + red[2][1] + red[3][1];
    int bid = blockIdx.y * gridDim.x + blockIdx.x;   // 0..383
    partials[((size_t)net * 384 + bid) * 2 + 0] = S;
    partials[((size_t)net * 384 + bid) * 2 + 1] = Q;
  }
}

// ---------------------------------------------------------------------------
// Kernel 3: reduce 384 per-block partials -> stats[net] = {sum, sumsq}
// ---------------------------------------------------------------------------
__global__ __launch_bounds__(256) void finalize_stats_kernel(
    const double* __restrict__ partials, double* __restrict__ stats) {
  int net = blockIdx.x;
  const double* P = partials + (size_t)net * 384 * 2;
  int tid = threadIdx.x;
  double s = 0.0, q = 0.0;
  for (int i = tid; i < 384; i += 256) {
    s += P[i * 2 + 0];
    q += P[i * 2 + 1];
  }
#pragma unroll
  for (int off = 32; off > 0; off >>= 1) {
    s += __shfl_down(s, off);
    q += __shfl_down(q, off);
  }
  __shared__ double red[4][2];
  int wave = tid >> 6, lane = tid & 63;
  if (lane == 0) { red[wave][0] = s; red[wave][1] = q; }
  __syncthreads();
  if (tid == 0) {
    stats[net * 2 + 0] = red[0][0] + red[1][0] + red[2][0] + red[3][0];
    stats[net * 2 + 1] = red[0][1] + red[1][1] + red[2][1] + red[3][1];
  }
}

// ---------------------------------------------------------------------------
// Kernel 4: full-tensor layernorm -> sigmoid -> threefry bernoulli mask ->
//           x += cross*mask, x kept as f16 hi/lo pairs (exact fp32 recon).
// (partitionable mapping: bits[j] = o0^o1 of threefry(key, hi=0, lo=j))
// ---------------------------------------------------------------------------
__global__ __launch_bounds__(256) void mask_update_kernel(
    _Float16* __restrict__ xdh, _Float16* __restrict__ xdl,
    _Float16* __restrict__ xsh, _Float16* __restrict__ xsl,
    const float* __restrict__ crd, const float* __restrict__ crs,
    const double* __restrict__ stats,
    uint32_t kd0, uint32_t kd1, uint32_t ks0, uint32_t ks1) {
  const int net = blockIdx.y;
  _Float16* xh = net ? xsh : xdh;
  _Float16* xl = net ? xsl : xdl;
  const float* cr = net ? crs : crd;
  const uint32_t k0 = net ? ks0 : kd0;
  const uint32_t k1 = net ? ks1 : kd1;

  const double invN = 1.0 / (double)NTOT;
  double meand = stats[net * 2 + 0] * invN;
  double vard  = stats[net * 2 + 1] * invN - meand * meand;
  float m  = (float)meand;
  float v  = (float)vard;
  float sv = v + 1e-5f;
  float rs = (float)(1.0 / sqrt((double)sv));

  uint32_t j = blockIdx.x * 256u + threadIdx.x;  // 0..NTOT-1
  float c = cr[j];
  float ln = (c - m) * rs;
  float p = (float)sigmoid_d((double)ln);
  uint32_t o0, o1;
  threefry2x32(k0, k1, 0u, j, o0, o1);
  uint32_t bits = o0 ^ o1;
  float u = __uint_as_float(0x3F800000u | (bits >> 9)) - 1.0f;

  float xv = (float)xh[j] + (float)xl[j];   // exact reconstruction
  if (u < p) xv += c;
  _Float16 h = (_Float16)xv;
  xh[j] = h;
  xl[j] = (_Float16)(xv - (float)h);
}

// ---------------------------------------------------------------------------
// Kernel 5: heads. One wave per row: 4 dot products, sigmoids, y_pred_d,
// per-block fp64 BCE partials. x read from hi/lo pairs.
// ---------------------------------------------------------------------------
__global__ __launch_bounds__(256) void head_kernel(
    const _Float16* __restrict__ xdh, const _Float16* __restrict__ xdl,
    const _Float16* __restrict__ xsh, const _Float16* __restrict__ xsl,
    const float* __restrict__ wfd, const float* __restrict__ wfs,
    const float* __restrict__ bfd_p, const float* __restrict__ bfs_p,
    const float* __restrict__ y_true,
    float* __restrict__ out, double* __restrict__ bce_part) {
  const int wave = threadIdx.x >> 6;
  const int lane = threadIdx.x & 63;
  const int row = blockIdx.x * 4 + wave;
  const size_t base = (size_t)row * DIM;

  float dd = 0.f, dsw = 0.f, sd = 0.f, ssw = 0.f;
  for (int t = lane; t < DIM; t += 64) {
    float vd = (float)xdh[base + t] + (float)xdl[base + t];
    float vs = (float)xsh[base + t] + (float)xsl[base + t];
    float wd = wfd[t], ws = wfs[t];
    dd  = fmaf(vd, wd, dd);
    dsw = fmaf(vd, ws, dsw);
    sd  = fmaf(vs, wd, sd);
    ssw = fmaf(vs, ws, ssw);
  }
#pragma unroll
  for (int off = 32; off > 0; off >>= 1) {
    dd  += __shfl_down(dd, off);
    dsw += __shfl_down(dsw, off);
    sd  += __shfl_down(sd, off);
    ssw += __shfl_down(ssw, off);
  }
  __shared__ double redd[4], reds[4];
  if (lane == 0) {
    float bfd = *bfd_p, bfs = *bfs_p;
    double sdd = sigmoid_d((double)(dd + bfd));    // fc_d(x_d)
    double ssd = sigmoid_d((double)(dsw + bfs));   // fc_s(x_d)
    double sds = sigmoid_d((double)(sd + bfd));    // fc_d(x_s)
    double sss = sigmoid_d((double)(ssw + bfs));   // fc_s(x_s)
    double ypd = 0.5 * (sdd + sss);
    double yps = 0.5 * (sds + ssd);
    out[row] = (float)ypd;
    double y = (double)y_true[row];
    redd[wave] = -(y * log(ypd) + (1.0 - y) * log(1.0 - ypd));
    reds[wave] = -(y * log(yps) + (1.0 - y) * log(1.0 - yps));
  }
  __syncthreads();
  if (threadIdx.x == 0) {
    bce_part[(size_t)blockIdx.x * 2 + 0] = redd[0] + redd[1] + redd[2] + redd[3];
    bce_part[(size_t)blockIdx.x * 2 + 1] = reds[0] + reds[1] + reds[2] + reds[3];
  }
}

// ---------------------------------------------------------------------------
// Kernel 6: reduce BCE partials -> tri_loss
// ---------------------------------------------------------------------------
__global__ __launch_bounds__(256) void loss_kernel(
    const double* __restrict__ bce_part, float* __restrict__ out_tri) {
  int tid = threadIdx.x;
  double sdl = 0.0, ssl = 0.0;
  for (int i = tid; i < 2048; i += 256) {
    sdl += bce_part[i * 2 + 0];
    ssl += bce_part[i * 2 + 1];
  }
#pragma unroll
  for (int off = 32; off > 0; off >>= 1) {
    sdl += __shfl_down(sdl, off);
    ssl += __shfl_down(ssl, off);
  }
  __shared__ double red[4][2];
  int wave = tid >> 6, lane = tid & 63;
  if (lane == 0) { red[wave][0] = sdl; red[wave][1] = ssl; }
  __syncthreads();
  if (tid == 0) {
    double loss_d = (red[0][0] + red[1][0] + red[2][0] + red[3][0]) / (double)BATCH;
    double loss_s = (red[0][1] + red[1][1] + red[2][1] + red[3][1]) / (double)BATCH;
    double bce = loss_d + loss_s;
    double wd = fmax(0.0, loss_d - bce);
    double ws = fmax(0.0, loss_s - bce);
    out_tri[0] = (float)(bce + wd * loss_d + ws * loss_s);
  }
}

// ---------------------------------------------------------------------------
// Launch
// ---------------------------------------------------------------------------
extern "C" void kernel_launch(void* const* d_in, const int* in_sizes, int n_in,
                              void* d_out, int out_size, void* d_ws, size_t ws_size,
                              hipStream_t stream) {
  const int* x_p = (const int*)d_in[0];
  const int* x_a = (const int*)d_in[1];
  const int* x_c = (const int*)d_in[2];
  const float* y_true = (const float*)d_in[3];
  const float* E0 = (const float*)d_in[4];
  const float* E1 = (const float*)d_in[5];
  const float* E2 = (const float*)d_in[6];
  const float* Wd = (const float*)d_in[7];
  const float* bd = (const float*)d_in[8];
  const float* Ws = (const float*)d_in[9];
  const float* bs = (const float*)d_in[10];
  const float* wfd = (const float*)d_in[11];
  const float* bfd = (const float*)d_in[12];
  const float* wfs = (const float*)d_in[13];
  const float* bfs = (const float*)d_in[14];
  float* out = (float*)d_out;

  // workspace layout (bytes; keep doubles 8B-aligned)
  char* p = (char*)d_ws;
  float* crd = (float*)p;                 p += (size_t)NTOT * 4;
  float* crs = (float*)p;                 p += (size_t)NTOT * 4;
  double* partials = (double*)p;          p += (size_t)2 * 384 * 2 * 8;
  double* stats    = (double*)p;          p += 4 * 8;
  double* bce_part = (double*)p;          p += (size_t)2048 * 2 * 8;
  _Float16* xdh = (_Float16*)p;           p += (size_t)NTOT * 2;
  _Float16* xdl = (_Float16*)p;           p += (size_t)NTOT * 2;
  _Float16* xsh = (_Float16*)p;           p += (size_t)NTOT * 2;
  _Float16* xsl = (_Float16*)p;           p += (size_t)NTOT * 2;
  _Float16* Wh  = (_Float16*)p;           p += (size_t)2 * NLAYERS * DIM * DIM * 2;
  _Float16* Wl  = (_Float16*)p;           p += (size_t)2 * NLAYERS * DIM * DIM * 2;

  gather_kernel<<<NTOT / 256, 256, 0, stream>>>(
      x_p, x_a, x_c, E0, E1, E2, xdh, xdl, xsh, xsl);
  split_w_kernel<<<2 * NLAYERS * DIM * DIM / 256, 256, 0, stream>>>(Wd, Ws, Wh, Wl);

  for (int l = 0; l < NLAYERS; ++l) {
    gemm_mfma_kernel<<<dim3(6, 64, 2), 256, 0, stream>>>(
        xdh, xdl, xsh, xsl, Wh, Wl, bd, bs, crd, crs, partials, l);
    finalize_stats_kernel<<<2, 256, 0, stream>>>(partials, stats);
    uint32_t kd0, kd1, ks0, ks1;
    threefry2x32(0u, 42u, 0u, (uint32_t)l, kd0, kd1);
    threefry2x32(0u, 42u, 0u, (uint32_t)(4 + l), ks0, ks1);
    mask_update_kernel<<<dim3(NTOT / 256, 2), 256, 0, stream>>>(
        xdh, xdl, xsh, xsl, crd, crs, stats, kd0, kd1, ks0, ks1);
  }

  head_kernel<<<BATCH / 4, 256, 0, stream>>>(
      xdh, xdl, xsh, xsl, wfd, wfs, bfd, bfs, y_true, out, bce_part);
  loss_kernel<<<1, 256, 0, stream>>>(bce_part, out + BATCH);
}

// Round 6
// 800.533 us; speedup vs baseline: 2.0449x; 1.4749x over previous
//
#include <hip/hip_runtime.h>
#include <hip/hip_bf16.h>
#include <cstdint>
#include <cstddef>

// Problem constants
#define BATCH   8192
#define DIM     768
#define NTOT    6291456      // BATCH*DIM
#define NLAYERS 4

typedef _Float16 half8 __attribute__((ext_vector_type(8)));
typedef float    f32x4 __attribute__((ext_vector_type(4)));

#define AS_GLOBAL __attribute__((address_space(1)))
#define AS_LDS    __attribute__((address_space(3)))

// async 16B global->LDS copy; lds dst is wave-uniform base + lane*16
__device__ __forceinline__ void async_copy16(const void* g, void* l) {
  __builtin_amdgcn_global_load_lds((AS_GLOBAL const uint32_t*)g,
                                   (AS_LDS uint32_t*)l, 16, 0, 0);
}

// ---------------------------------------------------------------------------
// Threefry-2x32 (matches jax/_src/prng.py exactly; 20 rounds, 5 key injections)
// ---------------------------------------------------------------------------
__host__ __device__ __forceinline__ uint32_t rotl32(uint32_t v, int d) {
  return (v << d) | (v >> (32 - d));
}

__host__ __device__ __forceinline__ void threefry2x32(
    uint32_t k0, uint32_t k1, uint32_t x0, uint32_t x1,
    uint32_t& o0, uint32_t& o1) {
  uint32_t ks2 = k0 ^ k1 ^ 0x1BD11BDAu;
  x0 += k0; x1 += k1;
#define TF_R(r) { x0 += x1; x1 = rotl32(x1, (r)) ^ x0; }
  TF_R(13) TF_R(15) TF_R(26) TF_R(6)
  x0 += k1; x1 += ks2 + 1u;
  TF_R(17) TF_R(29) TF_R(16) TF_R(24)
  x0 += ks2; x1 += k0 + 2u;
  TF_R(13) TF_R(15) TF_R(26) TF_R(6)
  x0 += k0; x1 += k1 + 3u;
  TF_R(17) TF_R(29) TF_R(16) TF_R(24)
  x0 += k1; x1 += ks2 + 4u;
  TF_R(13) TF_R(15) TF_R(26) TF_R(6)
  x0 += ks2; x1 += k0 + 5u;
#undef TF_R
  o0 = x0; o1 = x1;
}

__device__ __forceinline__ double sigmoid_d(double x) {
  return 1.0 / (1.0 + exp(-x));
}

// ---------------------------------------------------------------------------
// Kernel 1: embedding gather -> x as f16 hi/lo pairs for both nets
// ---------------------------------------------------------------------------
__global__ __launch_bounds__(256) void gather_kernel(
    const int* __restrict__ x_p, const int* __restrict__ x_a,
    const int* __restrict__ x_c,
    const float* __restrict__ E0, const float* __restrict__ E1,
    const float* __restrict__ E2,
    _Float16* __restrict__ xdh, _Float16* __restrict__ xdl,
    _Float16* __restrict__ xsh, _Float16* __restrict__ xsl) {
  int j = blockIdx.x * 256 + threadIdx.x;      // 0 .. NTOT-1
  int b = j / DIM;
  int f = j - b * DIM;
  int half_ = f / 384;         // 0 or 1
  int w = f - half_ * 384;     // 0..383
  int t = w >> 7;              // table 0..2
  int c = (w & 127) + (half_ << 7);
  int idx;
  const float* E;
  if (t == 0)      { E = E0; idx = x_p[b]; }
  else if (t == 1) { E = E1; idx = x_a[b]; }
  else             { E = E2; idx = x_c[b]; }
  float v = E[(size_t)idx * 256 + c];
  _Float16 h = (_Float16)v;
  _Float16 l = (_Float16)(v - (float)h);
  xdh[j] = h; xdl[j] = l;
  xsh[j] = h; xsl[j] = l;
}

// ---------------------------------------------------------------------------
// Kernel 1b: split all W (both nets, all layers) into f16 hi/lo
// layout: [net][layer][o][k], net-major = concat(Wd, Ws)
// ---------------------------------------------------------------------------
__global__ __launch_bounds__(256) void split_w_kernel(
    const float* __restrict__ Wd, const float* __restrict__ Ws,
    _Float16* __restrict__ Wh, _Float16* __restrict__ Wl) {
  int idx = blockIdx.x * 256 + threadIdx.x;    // 0 .. 2*4*768*768-1
  const int perNet = NLAYERS * DIM * DIM;
  float v = (idx < perNet) ? Wd[idx] : Ws[idx - perNet];
  _Float16 h = (_Float16)v;
  Wh[idx] = h;
  Wl[idx] = (_Float16)(v - (float)h);
}

// ---------------------------------------------------------------------------
// Kernel 2: MFMA GEMM, f16 hi/lo 3-term split, LDS-staged (m97 structure).
//   cross[m][n] = sum_k X[m][k] * W[n][k] + bias[n]
// 128x128 block tile, BK=32, 4 waves 2x2 -> each wave 64x64 = 4x4 of 16x16x32.
// LDS per array: 128 rows x 5 granules(16B) = 10240 B; granule (row,kk<4) at
// slot row*5+kk; slot row*5+4 is pad (staged as dup of kk=0, never read).
// Frag ds_read bank-quad = (5*row + quad) mod 8 -> balanced (8 lanes/quad).
// Staging: wave w stages array w (Ah,Al,Bh,Bl) with 10x global_load_lds 16B.
// acc += Ah*Bh + Al*Bh + Ah*Bl   (lo*lo dropped, ~2^-22 relative)
// Grid (x=m 64, y=n 6, z=net): m-fastest so round-robin XCD assignment keeps
// A m-stripes XCD-local (fix for R3's 8x A over-fetch).
// ---------------------------------------------------------------------------
__global__ __launch_bounds__(256, 3) void gemm_mfma_kernel(
    const _Float16* __restrict__ xdh, const _Float16* __restrict__ xdl,
    const _Float16* __restrict__ xsh, const _Float16* __restrict__ xsl,
    const _Float16* __restrict__ Wh, const _Float16* __restrict__ Wl,
    const float* __restrict__ bd, const float* __restrict__ bs,
    float* __restrict__ crd, float* __restrict__ crs,
    double* __restrict__ partials, int layer) {
  const int net = blockIdx.z;
  const float* bias = (net ? bs : bd) + layer * DIM;
  float* C = net ? crs : crd;

  const int wave = threadIdx.x >> 6, lane = threadIdx.x & 63;
  const int quad = lane >> 4, l16 = lane & 15;
  const int m0 = blockIdx.x * 128;
  const int n0 = blockIdx.y * 128;

  // 4 regions x 5120 halves: [Ah, Al, Bh, Bl]
  __shared__ _Float16 lds[4 * 5120];

  // ---- staging setup: wave w stages array w ----
  const _Float16* gbase;
  int rowbase;
  switch (wave) {
    case 0:  gbase = net ? xsh : xdh; rowbase = m0; break;
    case 1:  gbase = net ? xsl : xdl; rowbase = m0; break;
    case 2:  gbase = Wh + ((size_t)net * NLAYERS + layer) * DIM * DIM; rowbase = n0; break;
    default: gbase = Wl + ((size_t)net * NLAYERS + layer) * DIM * DIM; rowbase = n0; break;
  }
  // per-lane source offsets (element units), k-invariant
  int soff[10];
#pragma unroll
  for (int j = 0; j < 10; ++j) {
    int s  = j * 64 + lane;                 // lds slot 0..639
    int r  = (s * 52429) >> 18;             // s / 5 (exact for s < 640)
    int kk = (s - 5 * r) & 3;               // pad slot (kk==4) -> dup kk=0
    soff[j] = (rowbase + r) * DIM + kk * 8;
  }
  _Float16* ldsw = &lds[wave * 5120];       // wave's staging region

  // ---- wave quadrant + fragment read offsets (k-invariant) ----
  const int wm = (wave >> 1) * 64, wn = (wave & 1) * 64;
  const int fslotA = ((wm + l16) * 5 + quad) * 8;   // + t*640 per m-tile
  const int fslotB = ((wn + l16) * 5 + quad) * 8;   // + t*640 per n-tile

  f32x4 acc[4][4];
#pragma unroll
  for (int i = 0; i < 4; ++i)
#pragma unroll
    for (int j = 0; j < 4; ++j) acc[i][j] = (f32x4){0.f, 0.f, 0.f, 0.f};

  for (int k0 = 0; k0 < DIM; k0 += 32) {
    __syncthreads();   // previous compute done before overwrite
#pragma unroll
    for (int j = 0; j < 10; ++j)
      async_copy16(gbase + soff[j] + k0, ldsw + j * 512);
    __syncthreads();   // drains vmcnt(0): staging complete

    half8 ah[4], al[4], bh[4], bl[4];
#pragma unroll
    for (int t = 0; t < 4; ++t) {
      ah[t] = *(const half8*)&lds[        fslotA + t * 640];
      al[t] = *(const half8*)&lds[ 5120 + fslotA + t * 640];
      bh[t] = *(const half8*)&lds[10240 + fslotB + t * 640];
      bl[t] = *(const half8*)&lds[15360 + fslotB + t * 640];
    }
#pragma unroll
    for (int mt = 0; mt < 4; ++mt)
#pragma unroll
      for (int nt = 0; nt < 4; ++nt) {
        f32x4 a = acc[mt][nt];
        a = __builtin_amdgcn_mfma_f32_16x16x32_f16(ah[mt], bh[nt], a, 0, 0, 0);
        a = __builtin_amdgcn_mfma_f32_16x16x32_f16(al[mt], bh[nt], a, 0, 0, 0);
        a = __builtin_amdgcn_mfma_f32_16x16x32_f16(ah[mt], bl[nt], a, 0, 0, 0);
        acc[mt][nt] = a;
      }
  }

  // epilogue: bias add, store, fp64 sum/sumsq partials
  float biasv[4];
#pragma unroll
  for (int nt = 0; nt < 4; ++nt) biasv[nt] = bias[n0 + wn + nt * 16 + l16];

  double s = 0.0, q = 0.0;
#pragma unroll
  for (int mt = 0; mt < 4; ++mt) {
#pragma unroll
    for (int nt = 0; nt < 4; ++nt) {
      int n = n0 + wn + nt * 16 + l16;
#pragma unroll
      for (int r = 0; r < 4; ++r) {
        int m = m0 + wm + mt * 16 + quad * 4 + r;
        float v = acc[mt][nt][r] + biasv[nt];
        C[(size_t)m * DIM + n] = v;
        s += (double)v;
        q += (double)v * (double)v;
      }
    }
  }
#pragma unroll
  for (int off = 32; off > 0; off >>= 1) {
    s += __shfl_down(s, off);
    q += __shfl_down(q, off);
  }
  __shared__ double red[4][2];
  if (lane == 0) { red[wave][0] = s; red[wave][1] = q; }
  __syncthreads();
  if (threadIdx.x == 0) {
    double S = red[0][0] + red[1][0] + red[2][0] + red[3][0];
    double Q = red[0][1] + red[1][1] + red[2][1] + red[3][1];
    int bid = blockIdx.y * 64 + blockIdx.x;   // 0..383
    partials[((size_t)net * 384 + bid) * 2 + 0] = S;
    partials[((size_t)net * 384 + bid) * 2 + 1] = Q;
  }
}

// ---------------------------------------------------------------------------
// Kernel 3: reduce 384 per-block partials -> stats[net] = {sum, sumsq}
// ---------------------------------------------------------------------------
__global__ __launch_bounds__(256) void finalize_stats_kernel(
    const double* __restrict__ partials, double* __restrict__ stats) {
  int net = blockIdx.x;
  const double* P = partials + (size_t)net * 384 * 2;
  int tid = threadIdx.x;
  double s = 0.0, q = 0.0;
  for (int i = tid; i < 384; i += 256) {
    s += P[i * 2 + 0];
    q += P[i * 2 + 1];
  }
#pragma unroll
  for (int off = 32; off > 0; off >>= 1) {
    s += __shfl_down(s, off);
    q += __shfl_down(q, off);
  }
  __shared__ double red[4][2];
  int wave = tid >> 6, lane = tid & 63;
  if (lane == 0) { red[wave][0] = s; red[wave][1] = q; }
  __syncthreads();
  if (tid == 0) {
    stats[net * 2 + 0] = red[0][0] + red[1][0] + red[2][0] + red[3][0];
    stats[net * 2 + 1] = red[0][1] + red[1][1] + red[2][1] + red[3][1];
  }
}

// ---------------------------------------------------------------------------
// Kernel 4: full-tensor layernorm -> sigmoid -> threefry bernoulli mask ->
//           x += cross*mask, x kept as f16 hi/lo pairs (exact fp32 recon).
// (partitionable mapping: bits[j] = o0^o1 of threefry(key, hi=0, lo=j))
// ---------------------------------------------------------------------------
__global__ __launch_bounds__(256) void mask_update_kernel(
    _Float16* __restrict__ xdh, _Float16* __restrict__ xdl,
    _Float16* __restrict__ xsh, _Float16* __restrict__ xsl,
    const float* __restrict__ crd, const float* __restrict__ crs,
    const double* __restrict__ stats,
    uint32_t kd0, uint32_t kd1, uint32_t ks0, uint32_t ks1) {
  const int net = blockIdx.y;
  _Float16* xh = net ? xsh : xdh;
  _Float16* xl = net ? xsl : xdl;
  const float* cr = net ? crs : crd;
  const uint32_t k0 = net ? ks0 : kd0;
  const uint32_t k1 = net ? ks1 : kd1;

  const double invN = 1.0 / (double)NTOT;
  double meand = stats[net * 2 + 0] * invN;
  double vard  = stats[net * 2 + 1] * invN - meand * meand;
  float m  = (float)meand;
  float v  = (float)vard;
  float sv = v + 1e-5f;
  float rs = (float)(1.0 / sqrt((double)sv));

  uint32_t j = blockIdx.x * 256u + threadIdx.x;  // 0..NTOT-1
  float c = cr[j];
  float ln = (c - m) * rs;
  float p = (float)sigmoid_d((double)ln);
  uint32_t o0, o1;
  threefry2x32(k0, k1, 0u, j, o0, o1);
  uint32_t bits = o0 ^ o1;
  float u = __uint_as_float(0x3F800000u | (bits >> 9)) - 1.0f;

  float xv = (float)xh[j] + (float)xl[j];   // exact reconstruction
  if (u < p) xv += c;
  _Float16 h = (_Float16)xv;
  xh[j] = h;
  xl[j] = (_Float16)(xv - (float)h);
}

// ---------------------------------------------------------------------------
// Kernel 5: heads. One wave per row: 4 dot products, sigmoids, y_pred_d,
// per-block fp64 BCE partials. x read from hi/lo pairs.
// ---------------------------------------------------------------------------
__global__ __launch_bounds__(256) void head_kernel(
    const _Float16* __restrict__ xdh, const _Float16* __restrict__ xdl,
    const _Float16* __restrict__ xsh, const _Float16* __restrict__ xsl,
    const float* __restrict__ wfd, const float* __restrict__ wfs,
    const float* __restrict__ bfd_p, const float* __restrict__ bfs_p,
    const float* __restrict__ y_true,
    float* __restrict__ out, double* __restrict__ bce_part) {
  const int wave = threadIdx.x >> 6;
  const int lane = threadIdx.x & 63;
  const int row = blockIdx.x * 4 + wave;
  const size_t base = (size_t)row * DIM;

  float dd = 0.f, dsw = 0.f, sd = 0.f, ssw = 0.f;
  for (int t = lane; t < DIM; t += 64) {
    float vd = (float)xdh[base + t] + (float)xdl[base + t];
    float vs = (float)xsh[base + t] + (float)xsl[base + t];
    float wd = wfd[t], ws = wfs[t];
    dd  = fmaf(vd, wd, dd);
    dsw = fmaf(vd, ws, dsw);
    sd  = fmaf(vs, wd, sd);
    ssw = fmaf(vs, ws, ssw);
  }
#pragma unroll
  for (int off = 32; off > 0; off >>= 1) {
    dd  += __shfl_down(dd, off);
    dsw += __shfl_down(dsw, off);
    sd  += __shfl_down(sd, off);
    ssw += __shfl_down(ssw, off);
  }
  __shared__ double redd[4], reds[4];
  if (lane == 0) {
    float bfd = *bfd_p, bfs = *bfs_p;
    double sdd = sigmoid_d((double)(dd + bfd));    // fc_d(x_d)
    double ssd = sigmoid_d((double)(dsw + bfs));   // fc_s(x_d)
    double sds = sigmoid_d((double)(sd + bfd));    // fc_d(x_s)
    double sss = sigmoid_d((double)(ssw + bfs));   // fc_s(x_s)
    double ypd = 0.5 * (sdd + sss);
    double yps = 0.5 * (sds + ssd);
    out[row] = (float)ypd;
    double y = (double)y_true[row];
    redd[wave] = -(y * log(ypd) + (1.0 - y) * log(1.0 - ypd));
    reds[wave] = -(y * log(yps) + (1.0 - y) * log(1.0 - yps));
  }
  __syncthreads();
  if (threadIdx.x == 0) {
    bce_part[(size_t)blockIdx.x * 2 + 0] = redd[0] + redd[1] + redd[2] + redd[3];
    bce_part[(size_t)blockIdx.x * 2 + 1] = reds[0] + reds[1] + reds[2] + reds[3];
  }
}

// ---------------------------------------------------------------------------
// Kernel 6: reduce BCE partials -> tri_loss
// ---------------------------------------------------------------------------
__global__ __launch_bounds__(256) void loss_kernel(
    const double* __restrict__ bce_part, float* __restrict__ out_tri) {
  int tid = threadIdx.x;
  double sdl = 0.0, ssl = 0.0;
  for (int i = tid; i < 2048; i += 256) {
    sdl += bce_part[i * 2 + 0];
    ssl += bce_part[i * 2 + 1];
  }
#pragma unroll
  for (int off = 32; off > 0; off >>= 1) {
    sdl += __shfl_down(sdl, off);
    ssl += __shfl_down(ssl, off);
  }
  __shared__ double red[4][2];
  int wave = tid >> 6, lane = tid & 63;
  if (lane == 0) { red[wave][0] = sdl; red[wave][1] = ssl; }
  __syncthreads();
  if (tid == 0) {
    double loss_d = (red[0][0] + red[1][0] + red[2][0] + red[3][0]) / (double)BATCH;
    double loss_s = (red[0][1] + red[1][1] + red[2][1] + red[3][1]) / (double)BATCH;
    double bce = loss_d + loss_s;
    double wd = fmax(0.0, loss_d - bce);
    double ws = fmax(0.0, loss_s - bce);
    out_tri[0] = (float)(bce + wd * loss_d + ws * loss_s);
  }
}

// ---------------------------------------------------------------------------
// Launch
// ---------------------------------------------------------------------------
extern "C" void kernel_launch(void* const* d_in, const int* in_sizes, int n_in,
                              void* d_out, int out_size, void* d_ws, size_t ws_size,
                              hipStream_t stream) {
  const int* x_p = (const int*)d_in[0];
  const int* x_a = (const int*)d_in[1];
  const int* x_c = (const int*)d_in[2];
  const float* y_true = (const float*)d_in[3];
  const float* E0 = (const float*)d_in[4];
  const float* E1 = (const float*)d_in[5];
  const float* E2 = (const float*)d_in[6];
  const float* Wd = (const float*)d_in[7];
  const float* bd = (const float*)d_in[8];
  const float* Ws = (const float*)d_in[9];
  const float* bs = (const float*)d_in[10];
  const float* wfd = (const float*)d_in[11];
  const float* bfd = (const float*)d_in[12];
  const float* wfs = (const float*)d_in[13];
  const float* bfs = (const float*)d_in[14];
  float* out = (float*)d_out;

  // workspace layout (bytes; keep doubles 8B-aligned)
  char* p = (char*)d_ws;
  float* crd = (float*)p;                 p += (size_t)NTOT * 4;
  float* crs = (float*)p;                 p += (size_t)NTOT * 4;
  double* partials = (double*)p;          p += (size_t)2 * 384 * 2 * 8;
  double* stats    = (double*)p;          p += 4 * 8;
  double* bce_part = (double*)p;          p += (size_t)2048 * 2 * 8;
  _Float16* xdh = (_Float16*)p;           p += (size_t)NTOT * 2;
  _Float16* xdl = (_Float16*)p;           p += (size_t)NTOT * 2;
  _Float16* xsh = (_Float16*)p;           p += (size_t)NTOT * 2;
  _Float16* xsl = (_Float16*)p;           p += (size_t)NTOT * 2;
  _Float16* Wh  = (_Float16*)p;           p += (size_t)2 * NLAYERS * DIM * DIM * 2;
  _Float16* Wl  = (_Float16*)p;           p += (size_t)2 * NLAYERS * DIM * DIM * 2;

  gather_kernel<<<NTOT / 256, 256, 0, stream>>>(
      x_p, x_a, x_c, E0, E1, E2, xdh, xdl, xsh, xsl);
  split_w_kernel<<<2 * NLAYERS * DIM * DIM / 256, 256, 0, stream>>>(Wd, Ws, Wh, Wl);

  for (int l = 0; l < NLAYERS; ++l) {
    gemm_mfma_kernel<<<dim3(64, 6, 2), 256, 0, stream>>>(
        xdh, xdl, xsh, xsl, Wh, Wl, bd, bs, crd, crs, partials, l);
    finalize_stats_kernel<<<2, 256, 0, stream>>>(partials, stats);
    uint32_t kd0, kd1, ks0, ks1;
    threefry2x32(0u, 42u, 0u, (uint32_t)l, kd0, kd1);
    threefry2x32(0u, 42u, 0u, (uint32_t)(4 + l), ks0, ks1);
    mask_update_kernel<<<dim3(NTOT / 256, 2), 256, 0, stream>>>(
        xdh, xdl, xsh, xsl, crd, crs, stats, kd0, kd1, ks0, ks1);
  }

  head_kernel<<<BATCH / 4, 256, 0, stream>>>(
      xdh, xdl, xsh, xsl, wfd, wfs, bfd, bfs, y_true, out, bce_part);
  loss_kernel<<<1, 256, 0, stream>>>(bce_part, out + BATCH);
}